// Round 17
// baseline (74.278 us; speedup 1.0000x reference)
//
#include <hip/hip_runtime.h>

#define NT 8
#define ND 16
#define NH 16
#define NW 16
#define NC 32
#define NB 65536
#define NCELLS (5 * 13 * 13)   // 845 span-base cells (t,d,h)
#define CAP 512                // per-cell slab; max expected ~333 (corner), 10sigma under
#define NCHB 16                // chunks per cell in fixed grid (16*32=512=CAP)

typedef _Float16 f16x8 __attribute__((ext_vector_type(8)));
typedef _Float16 half2v __attribute__((ext_vector_type(2)));
typedef float f32x16 __attribute__((ext_vector_type(16)));
typedef __attribute__((ext_vector_type(8))) _Float16 half8;

// ---- shared span-base logic (IDENTICAL in binning + main) ----
template <int N>
__device__ __forceinline__ int span_base(float u) {
    float s = u * (float)(N - 1);
    float fi = fminf(fmaxf(floorf(s), 0.0f), (float)(N - 2));
    int i = (int)fi;
    return (i == 0) ? 0 : ((i == N - 2) ? (N - 4) : (i - 1));
}

// Span b..b+3 (in-bounds) + 4 weights with linear-extrapolation padding
// folded in. Validated rounds 3-15 (absmax 7.8e-3).
template <int N>
__device__ __forceinline__ void dim_setup_span(float u, int& b, float w[4]) {
    float s = u * (float)(N - 1);
    float fi = fminf(fmaxf(floorf(s), 0.0f), (float)(N - 2));
    float t = s - fi;
    int i = (int)fi;
    float t2 = t * t, t3 = t2 * t;
    const float c6 = 1.0f / 6.0f;
    float w0 = (1.0f - 3.0f * t + 3.0f * t2 - t3) * c6;
    float w1 = (4.0f - 6.0f * t2 + 3.0f * t3) * c6;
    float w2 = (1.0f + 3.0f * t + 3.0f * t2 - 3.0f * t3) * c6;
    float w3 = t3 * c6;
    if (i == 0) {
        b = 0;
        w[0] = w1 + 2.0f * w0; w[1] = w2 - w0; w[2] = w3; w[3] = 0.0f;
    } else if (i == N - 2) {
        b = N - 4;
        w[0] = 0.0f; w[1] = w0; w[2] = w1 - w3; w[3] = w2 + 2.0f * w3;
    } else {
        b = i - 1;
        w[0] = w0; w[1] = w1; w[2] = w2; w[3] = w3;
    }
}

// ---- zero kernel: count[845] lives in an 8KB region ----
__global__ __launch_bounds__(512) void zero_meta_kernel(uint4* __restrict__ p) {
    p[threadIdx.x] = make_uint4(0, 0, 0, 0);   // 512 x 16B = 8KB
}

// ---- prep: blocks 0..255 transpose grid f32[row][w][c] -> f16 gT[row][c][w];
//            blocks 256..511 bin queries with LDS-aggregated two-level rank.
__global__ __launch_bounds__(256) void prep_kernel(
    const float* __restrict__ g, _Float16* __restrict__ gT,
    const float4* __restrict__ u4, int* __restrict__ count,
    int* __restrict__ perm) {
    __shared__ int lhist[NCELLS];
    __shared__ int lbase[NCELLS];

    int b = blockIdx.x;
    int t = threadIdx.x;
    if (b < 256) {
        int idx = b * 256 + t;          // 65536 = 2048 rows x 32 channels
        int row = idx >> 5;
        int c = idx & 31;
        const float* src = g + row * 512 + c;   // + w*32 strided reads
        union { _Float16 h[16]; uint4 u[2]; } outv;
#pragma unroll
        for (int w = 0; w < 16; ++w) outv.h[w] = (_Float16)src[w * 32];
        uint4* dst = (uint4*)(gT + (size_t)row * 512 + c * 16);
        dst[0] = outv.u[0];
        dst[1] = outv.u[1];
    } else {
        for (int c = t; c < NCELLS; c += 256) lhist[c] = 0;
        __syncthreads();

        int q = (b - 256) * 256 + t;
        float4 uu = u4[q];
        int bt = span_base<NT>(uu.x);
        int bd = span_base<ND>(uu.y);
        int bh = span_base<NH>(uu.z);
        int cell = (bt * 13 + bd) * 13 + bh;
        int lrank = atomicAdd(&lhist[cell], 1);
        __syncthreads();

        // one global atomic per distinct cell in this block
        for (int c = t; c < NCELLS; c += 256) {
            int n = lhist[c];
            lbase[c] = n ? atomicAdd(&count[c], n) : 0;
        }
        __syncthreads();

        int slot = lbase[cell] + lrank;
        if (slot < CAP) perm[cell * CAP + slot] = q;
    }
}

// ---- main: fixed grid NCELLS*NCHB blocks x 256 threads (4 waves).
// Chunk (cell, k32) -> 32 queries. out[q][c] = sum_{r,w} A[q][rw]*B[rw][c]:
// M=32 queries, N=32 channels, K = 64 rows x 16 w, split over 4 waves by
// t-index i (16 MFMA chain each), partials combined in LDS by wave 0.
// Layouts (cdna4_isa §10, m74/m101): A: m=l&31, k=8*(l>>5)+j;
// B: n=l&31, k=8*(l>>5)+j; C: col=l&31, row=(reg&3)+8*(reg>>2)+4*(l>>5).
// Numerics identical to round-14 kernel (verified absmax 7.8e-3).
__global__ __launch_bounds__(256) void spline4d_mfma_kernel(
    const float* __restrict__ u, const f16x8* __restrict__ gT,
    const int* __restrict__ count, const int* __restrict__ perm,
    float* __restrict__ out) {
    int cell = blockIdx.x >> 4;
    int k32 = blockIdx.x & (NCHB - 1);
    int n = min(count[cell], CAP);
    if (k32 * 32 >= n) return;           // uniform per block
    int len = min(32, n - k32 * 32);

    __shared__ float part[3][16][64];    // 12 KB partial C

    int bt = cell / 169;
    int r0 = cell - bt * 169;
    int bd = r0 / 13;
    int bh = r0 - bd * 13;

    int wid = (int)threadIdx.x >> 6;     // wave's t-index i
    int lane = (int)threadIdx.x & 63;
    int slot = lane & 31;
    int hi = lane >> 5;
    int c = lane & 31;

    int q = perm[cell * CAP + k32 * 32 + ((slot < len) ? slot : 0)];
    float4 uu = reinterpret_cast<const float4*>(u)[q];

    int xbt, xbd, xbh, bw;
    float wtv[4], wdv[4], whv[4], wwv[4];
    dim_setup_span<NT>(uu.x, xbt, wtv);
    dim_setup_span<ND>(uu.y, xbd, wdv);
    dim_setup_span<NH>(uu.z, xbh, whv);
    dim_setup_span<NW>(uu.w, bw, wwv);
    if (slot >= len) {                   // inactive lane: zero contribution
        wwv[0] = wwv[1] = wwv[2] = wwv[3] = 0.0f;
    }

    // lane's half of the 16-long sparse w-weight vector: w = hi*8 + 0..7
    half2v wf[4];
#pragma unroll
    for (int j2 = 0; j2 < 4; ++j2) {
        int w0 = hi * 8 + 2 * j2;
        int d0 = w0 - bw, d1 = w0 + 1 - bw;
        float v0 = (d0 == 0) ? wwv[0] : (d0 == 1) ? wwv[1]
                 : (d0 == 2) ? wwv[2] : (d0 == 3) ? wwv[3] : 0.0f;
        float v1 = (d1 == 0) ? wwv[0] : (d1 == 1) ? wwv[1]
                 : (d1 == 2) ? wwv[2] : (d1 == 3) ? wwv[3] : 0.0f;
        wf[j2][0] = (_Float16)v0;
        wf[j2][1] = (_Float16)v1;
    }

    // B pointer: gT row = 512 f16 = 64 f16x8; lane reads f16x8 (c*2 + hi).
    const f16x8* gp = gT + (c * 2 + hi);

    f32x16 acc;
#pragma unroll
    for (int e = 0; e < 16; ++e) acc[e] = 0.0f;

    float wti = wtv[wid];
#pragma unroll
    for (int j = 0; j < 4; ++j) {
        float wtd = wti * wdv[j];
        int rb = ((bt + wid) * ND + (bd + j)) * NH + bh;
#pragma unroll
        for (int k = 0; k < 4; ++k) {
            _Float16 wh = (_Float16)(wtd * whv[k]);
            half2v wb = {wh, wh};
            union { f16x8 v; half2v h[4]; } A;
            A.h[0] = wb * wf[0];
            A.h[1] = wb * wf[1];
            A.h[2] = wb * wf[2];
            A.h[3] = wb * wf[3];
            f16x8 B = gp[(rb + k) * 64];
            acc = __builtin_amdgcn_mfma_f32_32x32x16_f16(A.v, B, acc, 0, 0, 0);
        }
    }

    // combine partials: waves 1..3 -> LDS; wave 0 sums + writes C.
    if (wid > 0) {
#pragma unroll
        for (int r = 0; r < 16; ++r) part[wid - 1][r][lane] = acc[r];
    }
    __syncthreads();
    if (wid == 0) {
#pragma unroll
        for (int r = 0; r < 16; ++r)
            acc[r] += part[0][r][lane] + part[1][r][lane] + part[2][r][lane];

#pragma unroll
        for (int reg = 0; reg < 16; ++reg) {
            int sreg = (reg & 3) + 8 * (reg >> 2) + 4 * hi;
            int qs = __shfl(q, sreg);
            if (sreg < len) out[(size_t)qs * NC + c] = acc[reg];
        }
    }
}

// ---- fallback (ws too small): round-6 direct fp16 (52.5us proven) ----
typedef __attribute__((ext_vector_type(4))) _Float16 half4;

union H8 {
    half8 v;
    half2v h2[4];
};

__global__ __launch_bounds__(256) void convert_fp16_kernel(
    const float4* __restrict__ g, half4* __restrict__ hg) {
    int i = blockIdx.x * blockDim.x + threadIdx.x;
    float4 v = g[i];
    half4 h;
    h[0] = (_Float16)v.x;
    h[1] = (_Float16)v.y;
    h[2] = (_Float16)v.z;
    h[3] = (_Float16)v.w;
    hg[i] = h;
}

__global__ __launch_bounds__(256) void spline4d_fp16_kernel(
    const float* __restrict__ u, const half8* __restrict__ grid,
    float4* __restrict__ out) {
    int tid = blockIdx.x * blockDim.x + threadIdx.x;
    int q = tid >> 4;
    int s = tid & 15;

    float4 uu = reinterpret_cast<const float4*>(u)[q];

    int bt, bd, bh, bw;
    float wtv[4], wdv[4], whv[4], wwv[4];
    dim_setup_span<NT>(uu.x, bt, wtv);
    dim_setup_span<ND>(uu.y, bd, wdv);
    dim_setup_span<NH>(uu.z, bh, whv);
    dim_setup_span<NW>(uu.w, bw, wwv);

    int wp = s >> 2;
    float wlane = (wp & 2) ? ((wp & 1) ? wwv[3] : wwv[2])
                           : ((wp & 1) ? wwv[1] : wwv[0]);

    half2v whW2[4];
#pragma unroll
    for (int k = 0; k < 4; ++k) {
        _Float16 h = (_Float16)(whv[k] * wlane);
        whW2[k][0] = h;
        whW2[k][1] = h;
    }

    int base = ((((bt * ND + bd) * NH + bh) * NW + bw) << 2) + s;

    float facc[8];
#pragma unroll
    for (int c = 0; c < 8; ++c) facc[c] = 0.0f;
    half2v a01 = {0, 0}, a23 = {0, 0}, a45 = {0, 0}, a67 = {0, 0};

#pragma unroll
    for (int i = 0; i < 4; ++i) {
#pragma unroll
        for (int j = 0; j < 4; ++j) {
            _Float16 wtdh = (_Float16)(wtv[i] * wdv[j]);
            half2v wtd2 = {wtdh, wtdh};
#pragma unroll
            for (int k = 0; k < 4; ++k) {
                int a = base + i * (4 * ND * NH * NW) + j * (4 * NH * NW) +
                        k * (4 * NW);
                H8 P;
                P.v = grid[a];
                half2v uw = wtd2 * whW2[k];
                a01 += P.h2[0] * uw;
                a23 += P.h2[1] * uw;
                a45 += P.h2[2] * uw;
                a67 += P.h2[3] * uw;
            }
        }
        if (i == 1 || i == 3) {
            facc[0] += (float)a01[0]; facc[1] += (float)a01[1];
            facc[2] += (float)a23[0]; facc[3] += (float)a23[1];
            facc[4] += (float)a45[0]; facc[5] += (float)a45[1];
            facc[6] += (float)a67[0]; facc[7] += (float)a67[1];
            a01 = (half2v){0, 0}; a23 = (half2v){0, 0};
            a45 = (half2v){0, 0}; a67 = (half2v){0, 0};
        }
    }

#pragma unroll
    for (int c = 0; c < 8; ++c) {
        facc[c] += __shfl_xor(facc[c], 4);
        facc[c] += __shfl_xor(facc[c], 8);
    }

    if (s < 4) {
        out[q * 8 + s * 2] = make_float4(facc[0], facc[1], facc[2], facc[3]);
        out[q * 8 + s * 2 + 1] = make_float4(facc[4], facc[5], facc[6], facc[7]);
    }
}

extern "C" void kernel_launch(void* const* d_in, const int* in_sizes, int n_in,
                              void* d_out, int out_size, void* d_ws, size_t ws_size,
                              hipStream_t stream) {
    const float* u = (const float*)d_in[0];
    const float* grid_f32 = (const float*)d_in[1];

    const size_t n_grid_floats = (size_t)NT * ND * NH * NW * NC;  // 1,048,576
    const size_t GT_BYTES = n_grid_floats * 2;                    // 2 MiB

    char* ws = (char*)d_ws;
    const size_t OFF_COUNT = GT_BYTES;                   // 845*4 in 8KB slot
    const size_t OFF_PERM = OFF_COUNT + 8192;            // 845*512*4 = 1.73MB
    const size_t NEED = OFF_PERM + (size_t)NCELLS * CAP * 4;   // ~3.8 MB

    if (ws_size >= NEED) {
        _Float16* gT = (_Float16*)ws;
        int* count = (int*)(ws + OFF_COUNT);
        int* perm = (int*)(ws + OFF_PERM);

        zero_meta_kernel<<<1, 512, 0, stream>>>((uint4*)(ws + OFF_COUNT));
        prep_kernel<<<512, 256, 0, stream>>>(
            grid_f32, gT, (const float4*)u, count, perm);
        spline4d_mfma_kernel<<<NCELLS * NCHB, 256, 0, stream>>>(
            u, (const f16x8*)gT, count, perm, (float*)d_out);
    } else if (ws_size >= GT_BYTES) {
        half4* hgrid = (half4*)ws;
        int cvt_blocks = (int)(n_grid_floats / 4 / 256);  // 1024
        convert_fp16_kernel<<<cvt_blocks, 256, 0, stream>>>(
            (const float4*)grid_f32, hgrid);
        int nblocks = NB * 16 / 256;
        spline4d_fp16_kernel<<<nblocks, 256, 0, stream>>>(
            u, (const half8*)hgrid, (float4*)d_out);
    }
}

// Round 18
// 38.878 us; speedup vs baseline: 1.9105x; 1.9105x over previous
//
#include <hip/hip_runtime.h>

#define NT 8
#define ND 16
#define NH 16
#define NW 16
#define NC 32
#define NB 65536
#define NCELLS (5 * 13 * 13)   // 845 span-base cells (t,d,h)
#define CAP 512                // per-cell slab; max expected ~333
#define CHUNKQ 32              // queries per chunk == MFMA M
#define MAXCHUNKS (NCELLS + NB / CHUNKQ)   // 2893

typedef _Float16 f16x8 __attribute__((ext_vector_type(8)));
typedef _Float16 half2v __attribute__((ext_vector_type(2)));
typedef float f32x16 __attribute__((ext_vector_type(16)));
typedef __attribute__((ext_vector_type(8))) _Float16 half8;

// ---- shared span-base logic (IDENTICAL in binning + main) ----
template <int N>
__device__ __forceinline__ int span_base(float u) {
    float s = u * (float)(N - 1);
    float fi = fminf(fmaxf(floorf(s), 0.0f), (float)(N - 2));
    int i = (int)fi;
    return (i == 0) ? 0 : ((i == N - 2) ? (N - 4) : (i - 1));
}

// Span b..b+3 (in-bounds) + 4 weights with linear-extrapolation padding
// folded in. Validated rounds 3-17 (absmax 7.8e-3).
template <int N>
__device__ __forceinline__ void dim_setup_span(float u, int& b, float w[4]) {
    float s = u * (float)(N - 1);
    float fi = fminf(fmaxf(floorf(s), 0.0f), (float)(N - 2));
    float t = s - fi;
    int i = (int)fi;
    float t2 = t * t, t3 = t2 * t;
    const float c6 = 1.0f / 6.0f;
    float w0 = (1.0f - 3.0f * t + 3.0f * t2 - t3) * c6;
    float w1 = (4.0f - 6.0f * t2 + 3.0f * t3) * c6;
    float w2 = (1.0f + 3.0f * t + 3.0f * t2 - 3.0f * t3) * c6;
    float w3 = t3 * c6;
    if (i == 0) {
        b = 0;
        w[0] = w1 + 2.0f * w0; w[1] = w2 - w0; w[2] = w3; w[3] = 0.0f;
    } else if (i == N - 2) {
        b = N - 4;
        w[0] = 0.0f; w[1] = w0; w[2] = w1 - w3; w[3] = w2 + 2.0f * w3;
    } else {
        b = i - 1;
        w[0] = w0; w[1] = w1; w[2] = w2; w[3] = w3;
    }
}

// ---- zero kernel: count (4KB slot) + nchunks (4KB slot) ----
__global__ __launch_bounds__(512) void zero_meta_kernel(uint4* __restrict__ p) {
    p[threadIdx.x] = make_uint4(0, 0, 0, 0);   // 8KB
}

// ---- prep: blocks 0..255 transpose grid f32[row][w][c] -> f16 gT[row][c][w];
//            blocks 256..511 bin queries (LDS two-level rank) + chunk records.
__global__ __launch_bounds__(256) void prep_kernel(
    const float* __restrict__ g, _Float16* __restrict__ gT,
    const float4* __restrict__ u4, int* __restrict__ count,
    int* __restrict__ perm, uint2* __restrict__ chunks,
    int* __restrict__ nchunks) {
    __shared__ int lhist[NCELLS];
    __shared__ int lbase[NCELLS];

    int b = blockIdx.x;
    int t = threadIdx.x;
    if (b < 256) {
        int idx = b * 256 + t;          // 65536 = 2048 rows x 32 channels
        int row = idx >> 5;
        int c = idx & 31;
        const float* src = g + row * 512 + c;
        union { _Float16 h[16]; uint4 u[2]; } outv;
#pragma unroll
        for (int w = 0; w < 16; ++w) outv.h[w] = (_Float16)src[w * 32];
        uint4* dst = (uint4*)(gT + (size_t)row * 512 + c * 16);
        dst[0] = outv.u[0];
        dst[1] = outv.u[1];
    } else {
        for (int c = t; c < NCELLS; c += 256) lhist[c] = 0;
        __syncthreads();

        int q = (b - 256) * 256 + t;
        float4 uu = u4[q];
        int bt = span_base<NT>(uu.x);
        int bd = span_base<ND>(uu.y);
        int bh = span_base<NH>(uu.z);
        int cell = (bt * 13 + bd) * 13 + bh;
        int lrank = atomicAdd(&lhist[cell], 1);
        __syncthreads();

        // one global atomic per distinct cell in this block
        for (int c = t; c < NCELLS; c += 256) {
            int n = lhist[c];
            lbase[c] = n ? atomicAdd(&count[c], n) : 0;
        }
        __syncthreads();

        int slot = lbase[cell] + lrank;
        if (slot < CAP) {
            perm[cell * CAP + slot] = q;
            // slots are dense per cell -> every 32-boundary slot exists once
            if ((slot & (CHUNKQ - 1)) == 0) {
                int cid = atomicAdd(nchunks, 1);
                uint2 rec;
                rec.x = (unsigned)(cell * CAP + slot);
                rec.y = (unsigned)cell | ((unsigned)(slot / CHUNKQ) << 16);
                chunks[cid] = rec;
            }
        }
    }
}

// ---- main: one wave (64 threads) per 32-query chunk (compact table, no
// empties, no LDS/barrier). 4 INDEPENDENT accumulator chains (one per
// t-index i): per (j,k) iteration 4 independent B loads + 4 independent
// MFMAs -> >=4 loads in flight, MFMA latency overlapped 4-way (r17 lesson:
// single-acc 64-chain was pure latency, MfmaUtil 3%).
// Layouts (cdna4_isa §10, m74/m101): A: m=l&31, k=8*(l>>5)+j;
// B: n=l&31, k=8*(l>>5)+j; C: col=l&31, row=(reg&3)+8*(reg>>2)+4*(l>>5).
// Numerics = round-14 kernel up to f32 summation order (verified 7.8e-3).
__global__ __launch_bounds__(64) void spline4d_mfma_kernel(
    const float* __restrict__ u, const f16x8* __restrict__ gT,
    const int* __restrict__ count, const int* __restrict__ perm,
    const uint2* __restrict__ chunks, const int* __restrict__ nchunks,
    float* __restrict__ out) {
    if ((int)blockIdx.x >= *nchunks) return;

    uint2 rec = chunks[blockIdx.x];
    int start = (int)rec.x;
    int cell = (int)(rec.y & 0xffffu);
    int k32 = (int)(rec.y >> 16);
    int n = min(count[cell], CAP);
    int len = min(CHUNKQ, n - k32 * CHUNKQ);

    int bt = cell / 169;
    int r0 = cell - bt * 169;
    int bd = r0 / 13;
    int bh = r0 - bd * 13;

    int lane = (int)threadIdx.x;
    int slot = lane & 31;
    int hi = lane >> 5;
    int c = lane & 31;

    int q = perm[start + ((slot < len) ? slot : 0)];
    float4 uu = reinterpret_cast<const float4*>(u)[q];

    int xbt, xbd, xbh, bw;
    float wtv[4], wdv[4], whv[4], wwv[4];
    dim_setup_span<NT>(uu.x, xbt, wtv);
    dim_setup_span<ND>(uu.y, xbd, wdv);
    dim_setup_span<NH>(uu.z, xbh, whv);
    dim_setup_span<NW>(uu.w, bw, wwv);
    if (slot >= len) {                   // inactive lane: zero contribution
        wwv[0] = wwv[1] = wwv[2] = wwv[3] = 0.0f;
    }

    // lane's half of the 16-long sparse w-weight vector: w = hi*8 + 0..7
    half2v wf[4];
#pragma unroll
    for (int j2 = 0; j2 < 4; ++j2) {
        int w0 = hi * 8 + 2 * j2;
        int d0 = w0 - bw, d1 = w0 + 1 - bw;
        float v0 = (d0 == 0) ? wwv[0] : (d0 == 1) ? wwv[1]
                 : (d0 == 2) ? wwv[2] : (d0 == 3) ? wwv[3] : 0.0f;
        float v1 = (d1 == 0) ? wwv[0] : (d1 == 1) ? wwv[1]
                 : (d1 == 2) ? wwv[2] : (d1 == 3) ? wwv[3] : 0.0f;
        wf[j2][0] = (_Float16)v0;
        wf[j2][1] = (_Float16)v1;
    }

    // B pointer: gT row = 512 f16 = 64 f16x8; lane reads f16x8 (c*2 + hi).
    const f16x8* gp = gT + (c * 2 + hi);
    // row index base for i=0: ((bt)*ND + (bd+j))*NH + bh + k ; i-stride in
    // rows = ND*NH = 256.
    int rbase0 = (bt * ND + bd) * NH + bh;

    f32x16 acc0, acc1, acc2, acc3;
#pragma unroll
    for (int e = 0; e < 16; ++e) { acc0[e] = 0.0f; acc1[e] = 0.0f;
                                   acc2[e] = 0.0f; acc3[e] = 0.0f; }

#pragma unroll
    for (int j = 0; j < 4; ++j) {
        float wd0 = wtv[0] * wdv[j];
        float wd1 = wtv[1] * wdv[j];
        float wd2 = wtv[2] * wdv[j];
        float wd3 = wtv[3] * wdv[j];
        int rj = rbase0 + j * NH;
#pragma unroll
        for (int k = 0; k < 4; ++k) {
            int r = rj + k;
            // 4 independent B loads (batched -> in flight together)
            f16x8 B0 = gp[(r          ) * 64];
            f16x8 B1 = gp[(r +     256) * 64];
            f16x8 B2 = gp[(r + 2 * 256) * 64];
            f16x8 B3 = gp[(r + 3 * 256) * 64];
            float whk = whv[k];
            _Float16 h0 = (_Float16)(wd0 * whk);
            _Float16 h1 = (_Float16)(wd1 * whk);
            _Float16 h2 = (_Float16)(wd2 * whk);
            _Float16 h3 = (_Float16)(wd3 * whk);
            half2v b0 = {h0, h0}, b1 = {h1, h1}, b2 = {h2, h2}, b3 = {h3, h3};
            union { f16x8 v; half2v h[4]; } A0, A1, A2, A3;
#pragma unroll
            for (int m = 0; m < 4; ++m) {
                A0.h[m] = b0 * wf[m];
                A1.h[m] = b1 * wf[m];
                A2.h[m] = b2 * wf[m];
                A3.h[m] = b3 * wf[m];
            }
            acc0 = __builtin_amdgcn_mfma_f32_32x32x16_f16(A0.v, B0, acc0, 0, 0, 0);
            acc1 = __builtin_amdgcn_mfma_f32_32x32x16_f16(A1.v, B1, acc1, 0, 0, 0);
            acc2 = __builtin_amdgcn_mfma_f32_32x32x16_f16(A2.v, B2, acc2, 0, 0, 0);
            acc3 = __builtin_amdgcn_mfma_f32_32x32x16_f16(A3.v, B3, acc3, 0, 0, 0);
        }
    }

#pragma unroll
    for (int e = 0; e < 16; ++e)
        acc0[e] = (acc0[e] + acc1[e]) + (acc2[e] + acc3[e]);

    // C: lane holds channel c for 16 queries (slots) sreg.
#pragma unroll
    for (int reg = 0; reg < 16; ++reg) {
        int sreg = (reg & 3) + 8 * (reg >> 2) + 4 * hi;
        int qs = __shfl(q, sreg);
        if (sreg < len) out[(size_t)qs * NC + c] = acc0[reg];
    }
}

// ---- fallback (ws too small): round-6 direct fp16 (52.5us proven) ----
typedef __attribute__((ext_vector_type(4))) _Float16 half4;

union H8 {
    half8 v;
    half2v h2[4];
};

__global__ __launch_bounds__(256) void convert_fp16_kernel(
    const float4* __restrict__ g, half4* __restrict__ hg) {
    int i = blockIdx.x * blockDim.x + threadIdx.x;
    float4 v = g[i];
    half4 h;
    h[0] = (_Float16)v.x;
    h[1] = (_Float16)v.y;
    h[2] = (_Float16)v.z;
    h[3] = (_Float16)v.w;
    hg[i] = h;
}

__global__ __launch_bounds__(256) void spline4d_fp16_kernel(
    const float* __restrict__ u, const half8* __restrict__ grid,
    float4* __restrict__ out) {
    int tid = blockIdx.x * blockDim.x + threadIdx.x;
    int q = tid >> 4;
    int s = tid & 15;

    float4 uu = reinterpret_cast<const float4*>(u)[q];

    int bt, bd, bh, bw;
    float wtv[4], wdv[4], whv[4], wwv[4];
    dim_setup_span<NT>(uu.x, bt, wtv);
    dim_setup_span<ND>(uu.y, bd, wdv);
    dim_setup_span<NH>(uu.z, bh, whv);
    dim_setup_span<NW>(uu.w, bw, wwv);

    int wp = s >> 2;
    float wlane = (wp & 2) ? ((wp & 1) ? wwv[3] : wwv[2])
                           : ((wp & 1) ? wwv[1] : wwv[0]);

    half2v whW2[4];
#pragma unroll
    for (int k = 0; k < 4; ++k) {
        _Float16 h = (_Float16)(whv[k] * wlane);
        whW2[k][0] = h;
        whW2[k][1] = h;
    }

    int base = ((((bt * ND + bd) * NH + bh) * NW + bw) << 2) + s;

    float facc[8];
#pragma unroll
    for (int c = 0; c < 8; ++c) facc[c] = 0.0f;
    half2v a01 = {0, 0}, a23 = {0, 0}, a45 = {0, 0}, a67 = {0, 0};

#pragma unroll
    for (int i = 0; i < 4; ++i) {
#pragma unroll
        for (int j = 0; j < 4; ++j) {
            _Float16 wtdh = (_Float16)(wtv[i] * wdv[j]);
            half2v wtd2 = {wtdh, wtdh};
#pragma unroll
            for (int k = 0; k < 4; ++k) {
                int a = base + i * (4 * ND * NH * NW) + j * (4 * NH * NW) +
                        k * (4 * NW);
                H8 P;
                P.v = grid[a];
                half2v uw = wtd2 * whW2[k];
                a01 += P.h2[0] * uw;
                a23 += P.h2[1] * uw;
                a45 += P.h2[2] * uw;
                a67 += P.h2[3] * uw;
            }
        }
        if (i == 1 || i == 3) {
            facc[0] += (float)a01[0]; facc[1] += (float)a01[1];
            facc[2] += (float)a23[0]; facc[3] += (float)a23[1];
            facc[4] += (float)a45[0]; facc[5] += (float)a45[1];
            facc[6] += (float)a67[0]; facc[7] += (float)a67[1];
            a01 = (half2v){0, 0}; a23 = (half2v){0, 0};
            a45 = (half2v){0, 0}; a67 = (half2v){0, 0};
        }
    }

#pragma unroll
    for (int c = 0; c < 8; ++c) {
        facc[c] += __shfl_xor(facc[c], 4);
        facc[c] += __shfl_xor(facc[c], 8);
    }

    if (s < 4) {
        out[q * 8 + s * 2] = make_float4(facc[0], facc[1], facc[2], facc[3]);
        out[q * 8 + s * 2 + 1] = make_float4(facc[4], facc[5], facc[6], facc[7]);
    }
}

extern "C" void kernel_launch(void* const* d_in, const int* in_sizes, int n_in,
                              void* d_out, int out_size, void* d_ws, size_t ws_size,
                              hipStream_t stream) {
    const float* u = (const float*)d_in[0];
    const float* grid_f32 = (const float*)d_in[1];

    const size_t n_grid_floats = (size_t)NT * ND * NH * NW * NC;  // 1,048,576
    const size_t GT_BYTES = n_grid_floats * 2;                    // 2 MiB

    char* ws = (char*)d_ws;
    const size_t OFF_COUNT = GT_BYTES;                   // 845*4, pad 4KB
    const size_t OFF_NCH = OFF_COUNT + 4096;             // 4B, pad 4KB
    const size_t OFF_CHUNKS = OFF_NCH + 4096;            // 2893*8 -> 24KB
    const size_t OFF_PERM = OFF_CHUNKS + 24576;          // 845*512*4 = 1.73MB
    const size_t NEED = OFF_PERM + (size_t)NCELLS * CAP * 4;   // ~3.8 MB

    if (ws_size >= NEED) {
        _Float16* gT = (_Float16*)ws;
        int* count = (int*)(ws + OFF_COUNT);
        int* nchunks = (int*)(ws + OFF_NCH);
        uint2* chunks = (uint2*)(ws + OFF_CHUNKS);
        int* perm = (int*)(ws + OFF_PERM);

        zero_meta_kernel<<<1, 512, 0, stream>>>((uint4*)(ws + OFF_COUNT));
        prep_kernel<<<512, 256, 0, stream>>>(
            grid_f32, gT, (const float4*)u, count, perm, chunks, nchunks);
        spline4d_mfma_kernel<<<MAXCHUNKS, 64, 0, stream>>>(
            u, (const f16x8*)gT, count, perm, chunks, nchunks, (float*)d_out);
    } else if (ws_size >= GT_BYTES) {
        half4* hgrid = (half4*)ws;
        int cvt_blocks = (int)(n_grid_floats / 4 / 256);  // 1024
        convert_fp16_kernel<<<cvt_blocks, 256, 0, stream>>>(
            (const float4*)grid_f32, hgrid);
        int nblocks = NB * 16 / 256;
        spline4d_fp16_kernel<<<nblocks, 256, 0, stream>>>(
            u, (const half8*)hgrid, (float4*)d_out);
    }
}

// Round 23
// 38.056 us; speedup vs baseline: 1.9518x; 1.0216x over previous
//
#include <hip/hip_runtime.h>

#define NT 8
#define ND 16
#define NH 16
#define NW 16
#define NC 32
#define NB 65536
#define NCELLS (5 * 13 * 13)   // 845 span-base cells (t,d,h)
#define CAP 512                // per-cell slab; max expected ~333
#define CHUNKQ 32              // queries per chunk == MFMA M
#define MAXCHUNKS (NCELLS + NB / CHUNKQ)   // 2893

typedef _Float16 f16x8 __attribute__((ext_vector_type(8)));
typedef _Float16 half2v __attribute__((ext_vector_type(2)));
typedef float f32x16 __attribute__((ext_vector_type(16)));
typedef __attribute__((ext_vector_type(8))) _Float16 half8;

// ---- shared span-base logic (IDENTICAL in binning + main) ----
template <int N>
__device__ __forceinline__ int span_base(float u) {
    float s = u * (float)(N - 1);
    float fi = fminf(fmaxf(floorf(s), 0.0f), (float)(N - 2));
    int i = (int)fi;
    return (i == 0) ? 0 : ((i == N - 2) ? (N - 4) : (i - 1));
}

// Span b..b+3 (in-bounds) + 4 weights with linear-extrapolation padding
// folded in. Validated rounds 3-18 (absmax 7.8e-3).
template <int N>
__device__ __forceinline__ void dim_setup_span(float u, int& b, float w[4]) {
    float s = u * (float)(N - 1);
    float fi = fminf(fmaxf(floorf(s), 0.0f), (float)(N - 2));
    float t = s - fi;
    int i = (int)fi;
    float t2 = t * t, t3 = t2 * t;
    const float c6 = 1.0f / 6.0f;
    float w0 = (1.0f - 3.0f * t + 3.0f * t2 - t3) * c6;
    float w1 = (4.0f - 6.0f * t2 + 3.0f * t3) * c6;
    float w2 = (1.0f + 3.0f * t + 3.0f * t2 - 3.0f * t3) * c6;
    float w3 = t3 * c6;
    if (i == 0) {
        b = 0;
        w[0] = w1 + 2.0f * w0; w[1] = w2 - w0; w[2] = w3; w[3] = 0.0f;
    } else if (i == N - 2) {
        b = N - 4;
        w[0] = 0.0f; w[1] = w0; w[2] = w1 - w3; w[3] = w2 + 2.0f * w3;
    } else {
        b = i - 1;
        w[0] = w0; w[1] = w1; w[2] = w2; w[3] = w3;
    }
}

// ---- zero kernel: count (4KB slot) + nchunks (4KB slot) ----
__global__ __launch_bounds__(512) void zero_meta_kernel(uint4* __restrict__ p) {
    p[threadIdx.x] = make_uint4(0, 0, 0, 0);   // 8KB
}

// ---- prep: blocks 0..255 transpose grid f32[row][w][c] -> f16 gT[row][c][w];
//            blocks 256..511 bin queries (LDS two-level rank) + chunk records.
__global__ __launch_bounds__(256) void prep_kernel(
    const float* __restrict__ g, _Float16* __restrict__ gT,
    const float4* __restrict__ u4, int* __restrict__ count,
    int* __restrict__ perm, uint2* __restrict__ chunks,
    int* __restrict__ nchunks) {
    __shared__ int lhist[NCELLS];
    __shared__ int lbase[NCELLS];

    int b = blockIdx.x;
    int t = threadIdx.x;
    if (b < 256) {
        int idx = b * 256 + t;          // 65536 = 2048 rows x 32 channels
        int row = idx >> 5;
        int c = idx & 31;
        const float* src = g + row * 512 + c;
        union { _Float16 h[16]; uint4 u[2]; } outv;
#pragma unroll
        for (int w = 0; w < 16; ++w) outv.h[w] = (_Float16)src[w * 32];
        uint4* dst = (uint4*)(gT + (size_t)row * 512 + c * 16);
        dst[0] = outv.u[0];
        dst[1] = outv.u[1];
    } else {
        for (int c = t; c < NCELLS; c += 256) lhist[c] = 0;
        __syncthreads();

        int q = (b - 256) * 256 + t;
        float4 uu = u4[q];
        int bt = span_base<NT>(uu.x);
        int bd = span_base<ND>(uu.y);
        int bh = span_base<NH>(uu.z);
        int cell = (bt * 13 + bd) * 13 + bh;
        int lrank = atomicAdd(&lhist[cell], 1);
        __syncthreads();

        // one global atomic per distinct cell in this block
        for (int c = t; c < NCELLS; c += 256) {
            int n = lhist[c];
            lbase[c] = n ? atomicAdd(&count[c], n) : 0;
        }
        __syncthreads();

        int slot = lbase[cell] + lrank;
        if (slot < CAP) {
            perm[cell * CAP + slot] = q;
            // slots are dense per cell -> every 32-boundary slot exists once
            if ((slot & (CHUNKQ - 1)) == 0) {
                int cid = atomicAdd(nchunks, 1);
                uint2 rec;
                rec.x = (unsigned)(cell * CAP + slot);
                rec.y = (unsigned)cell | ((unsigned)(slot / CHUNKQ) << 16);
                chunks[cid] = rec;
            }
        }
    }
}

// ---- main: one wave (64 threads) per 32-query chunk (compact table, no
// empties, no LDS/barrier). 4 INDEPENDENT accumulator chains (one per
// t-index i): per (j,k) iteration 4 independent B loads + 4 independent
// MFMAs -> >=4 loads in flight, MFMA latency overlapped 4-way.
// Layouts (cdna4_isa §10, m74/m101): A: m=l&31, k=8*(l>>5)+j;
// B: n=l&31, k=8*(l>>5)+j; C: col=l&31, row=(reg&3)+8*(reg>>2)+4*(l>>5).
// Verified round 18: passed, absmax 7.8e-3, total 38.9us.
__global__ __launch_bounds__(64) void spline4d_mfma_kernel(
    const float* __restrict__ u, const f16x8* __restrict__ gT,
    const int* __restrict__ count, const int* __restrict__ perm,
    const uint2* __restrict__ chunks, const int* __restrict__ nchunks,
    float* __restrict__ out) {
    if ((int)blockIdx.x >= *nchunks) return;

    uint2 rec = chunks[blockIdx.x];
    int start = (int)rec.x;
    int cell = (int)(rec.y & 0xffffu);
    int k32 = (int)(rec.y >> 16);
    int n = min(count[cell], CAP);
    int len = min(CHUNKQ, n - k32 * CHUNKQ);

    int bt = cell / 169;
    int r0 = cell - bt * 169;
    int bd = r0 / 13;
    int bh = r0 - bd * 13;

    int lane = (int)threadIdx.x;
    int slot = lane & 31;
    int hi = lane >> 5;
    int c = lane & 31;

    int q = perm[start + ((slot < len) ? slot : 0)];
    float4 uu = reinterpret_cast<const float4*>(u)[q];

    int xbt, xbd, xbh, bw;
    float wtv[4], wdv[4], whv[4], wwv[4];
    dim_setup_span<NT>(uu.x, xbt, wtv);
    dim_setup_span<ND>(uu.y, xbd, wdv);
    dim_setup_span<NH>(uu.z, xbh, whv);
    dim_setup_span<NW>(uu.w, bw, wwv);
    if (slot >= len) {                   // inactive lane: zero contribution
        wwv[0] = wwv[1] = wwv[2] = wwv[3] = 0.0f;
    }

    // lane's half of the 16-long sparse w-weight vector: w = hi*8 + 0..7
    half2v wf[4];
#pragma unroll
    for (int j2 = 0; j2 < 4; ++j2) {
        int w0 = hi * 8 + 2 * j2;
        int d0 = w0 - bw, d1 = w0 + 1 - bw;
        float v0 = (d0 == 0) ? wwv[0] : (d0 == 1) ? wwv[1]
                 : (d0 == 2) ? wwv[2] : (d0 == 3) ? wwv[3] : 0.0f;
        float v1 = (d1 == 0) ? wwv[0] : (d1 == 1) ? wwv[1]
                 : (d1 == 2) ? wwv[2] : (d1 == 3) ? wwv[3] : 0.0f;
        wf[j2][0] = (_Float16)v0;
        wf[j2][1] = (_Float16)v1;
    }

    // B pointer: gT row = 512 f16 = 64 f16x8; lane reads f16x8 (c*2 + hi).
    const f16x8* gp = gT + (c * 2 + hi);
    // row index base for i=0: ((bt)*ND + (bd+j))*NH + bh + k ; i-stride in
    // rows = ND*NH = 256.
    int rbase0 = (bt * ND + bd) * NH + bh;

    f32x16 acc0, acc1, acc2, acc3;
#pragma unroll
    for (int e = 0; e < 16; ++e) { acc0[e] = 0.0f; acc1[e] = 0.0f;
                                   acc2[e] = 0.0f; acc3[e] = 0.0f; }

#pragma unroll
    for (int j = 0; j < 4; ++j) {
        float wd0 = wtv[0] * wdv[j];
        float wd1 = wtv[1] * wdv[j];
        float wd2 = wtv[2] * wdv[j];
        float wd3 = wtv[3] * wdv[j];
        int rj = rbase0 + j * NH;
#pragma unroll
        for (int k = 0; k < 4; ++k) {
            int r = rj + k;
            // 4 independent B loads (batched -> in flight together)
            f16x8 B0 = gp[(r          ) * 64];
            f16x8 B1 = gp[(r +     256) * 64];
            f16x8 B2 = gp[(r + 2 * 256) * 64];
            f16x8 B3 = gp[(r + 3 * 256) * 64];
            float whk = whv[k];
            _Float16 h0 = (_Float16)(wd0 * whk);
            _Float16 h1 = (_Float16)(wd1 * whk);
            _Float16 h2 = (_Float16)(wd2 * whk);
            _Float16 h3 = (_Float16)(wd3 * whk);
            half2v b0 = {h0, h0}, b1 = {h1, h1}, b2 = {h2, h2}, b3 = {h3, h3};
            union { f16x8 v; half2v h[4]; } A0, A1, A2, A3;
#pragma unroll
            for (int m = 0; m < 4; ++m) {
                A0.h[m] = b0 * wf[m];
                A1.h[m] = b1 * wf[m];
                A2.h[m] = b2 * wf[m];
                A3.h[m] = b3 * wf[m];
            }
            acc0 = __builtin_amdgcn_mfma_f32_32x32x16_f16(A0.v, B0, acc0, 0, 0, 0);
            acc1 = __builtin_amdgcn_mfma_f32_32x32x16_f16(A1.v, B1, acc1, 0, 0, 0);
            acc2 = __builtin_amdgcn_mfma_f32_32x32x16_f16(A2.v, B2, acc2, 0, 0, 0);
            acc3 = __builtin_amdgcn_mfma_f32_32x32x16_f16(A3.v, B3, acc3, 0, 0, 0);
        }
    }

#pragma unroll
    for (int e = 0; e < 16; ++e)
        acc0[e] = (acc0[e] + acc1[e]) + (acc2[e] + acc3[e]);

    // C: lane holds channel c for 16 queries (slots) sreg.
#pragma unroll
    for (int reg = 0; reg < 16; ++reg) {
        int sreg = (reg & 3) + 8 * (reg >> 2) + 4 * hi;
        int qs = __shfl(q, sreg);
        if (sreg < len) out[(size_t)qs * NC + c] = acc0[reg];
    }
}

// ---- fallback (ws too small): round-6 direct fp16 (52.5us proven) ----
typedef __attribute__((ext_vector_type(4))) _Float16 half4;

union H8 {
    half8 v;
    half2v h2[4];
};

__global__ __launch_bounds__(256) void convert_fp16_kernel(
    const float4* __restrict__ g, half4* __restrict__ hg) {
    int i = blockIdx.x * blockDim.x + threadIdx.x;
    float4 v = g[i];
    half4 h;
    h[0] = (_Float16)v.x;
    h[1] = (_Float16)v.y;
    h[2] = (_Float16)v.z;
    h[3] = (_Float16)v.w;
    hg[i] = h;
}

__global__ __launch_bounds__(256) void spline4d_fp16_kernel(
    const float* __restrict__ u, const half8* __restrict__ grid,
    float4* __restrict__ out) {
    int tid = blockIdx.x * blockDim.x + threadIdx.x;
    int q = tid >> 4;
    int s = tid & 15;

    float4 uu = reinterpret_cast<const float4*>(u)[q];

    int bt, bd, bh, bw;
    float wtv[4], wdv[4], whv[4], wwv[4];
    dim_setup_span<NT>(uu.x, bt, wtv);
    dim_setup_span<ND>(uu.y, bd, wdv);
    dim_setup_span<NH>(uu.z, bh, whv);
    dim_setup_span<NW>(uu.w, bw, wwv);

    int wp = s >> 2;
    float wlane = (wp & 2) ? ((wp & 1) ? wwv[3] : wwv[2])
                           : ((wp & 1) ? wwv[1] : wwv[0]);

    half2v whW2[4];
#pragma unroll
    for (int k = 0; k < 4; ++k) {
        _Float16 h = (_Float16)(whv[k] * wlane);
        whW2[k][0] = h;
        whW2[k][1] = h;
    }

    int base = ((((bt * ND + bd) * NH + bh) * NW + bw) << 2) + s;

    float facc[8];
#pragma unroll
    for (int c = 0; c < 8; ++c) facc[c] = 0.0f;
    half2v a01 = {0, 0}, a23 = {0, 0}, a45 = {0, 0}, a67 = {0, 0};

#pragma unroll
    for (int i = 0; i < 4; ++i) {
#pragma unroll
        for (int j = 0; j < 4; ++j) {
            _Float16 wtdh = (_Float16)(wtv[i] * wdv[j]);
            half2v wtd2 = {wtdh, wtdh};
#pragma unroll
            for (int k = 0; k < 4; ++k) {
                int a = base + i * (4 * ND * NH * NW) + j * (4 * NH * NW) +
                        k * (4 * NW);
                H8 P;
                P.v = grid[a];
                half2v uw = wtd2 * whW2[k];
                a01 += P.h2[0] * uw;
                a23 += P.h2[1] * uw;
                a45 += P.h2[2] * uw;
                a67 += P.h2[3] * uw;
            }
        }
        if (i == 1 || i == 3) {
            facc[0] += (float)a01[0]; facc[1] += (float)a01[1];
            facc[2] += (float)a23[0]; facc[3] += (float)a23[1];
            facc[4] += (float)a45[0]; facc[5] += (float)a45[1];
            facc[6] += (float)a67[0]; facc[7] += (float)a67[1];
            a01 = (half2v){0, 0}; a23 = (half2v){0, 0};
            a45 = (half2v){0, 0}; a67 = (half2v){0, 0};
        }
    }

#pragma unroll
    for (int c = 0; c < 8; ++c) {
        facc[c] += __shfl_xor(facc[c], 4);
        facc[c] += __shfl_xor(facc[c], 8);
    }

    if (s < 4) {
        out[q * 8 + s * 2] = make_float4(facc[0], facc[1], facc[2], facc[3]);
        out[q * 8 + s * 2 + 1] = make_float4(facc[4], facc[5], facc[6], facc[7]);
    }
}

extern "C" void kernel_launch(void* const* d_in, const int* in_sizes, int n_in,
                              void* d_out, int out_size, void* d_ws, size_t ws_size,
                              hipStream_t stream) {
    const float* u = (const float*)d_in[0];
    const float* grid_f32 = (const float*)d_in[1];

    const size_t n_grid_floats = (size_t)NT * ND * NH * NW * NC;  // 1,048,576
    const size_t GT_BYTES = n_grid_floats * 2;                    // 2 MiB

    char* ws = (char*)d_ws;
    const size_t OFF_COUNT = GT_BYTES;                   // 845*4, pad 4KB
    const size_t OFF_NCH = OFF_COUNT + 4096;             // 4B, pad 4KB
    const size_t OFF_CHUNKS = OFF_NCH + 4096;            // 2893*8 -> 24KB
    const size_t OFF_PERM = OFF_CHUNKS + 24576;          // 845*512*4 = 1.73MB
    const size_t NEED = OFF_PERM + (size_t)NCELLS * CAP * 4;   // ~3.8 MB

    if (ws_size >= NEED) {
        _Float16* gT = (_Float16*)ws;
        int* count = (int*)(ws + OFF_COUNT);
        int* nchunks = (int*)(ws + OFF_NCH);
        uint2* chunks = (uint2*)(ws + OFF_CHUNKS);
        int* perm = (int*)(ws + OFF_PERM);

        zero_meta_kernel<<<1, 512, 0, stream>>>((uint4*)(ws + OFF_COUNT));
        prep_kernel<<<512, 256, 0, stream>>>(
            grid_f32, gT, (const float4*)u, count, perm, chunks, nchunks);
        spline4d_mfma_kernel<<<MAXCHUNKS, 64, 0, stream>>>(
            u, (const f16x8*)gT, count, perm, chunks, nchunks, (float*)d_out);
    } else if (ws_size >= GT_BYTES) {
        half4* hgrid = (half4*)ws;
        int cvt_blocks = (int)(n_grid_floats / 4 / 256);  // 1024
        convert_fp16_kernel<<<cvt_blocks, 256, 0, stream>>>(
            (const float4*)grid_f32, hgrid);
        int nblocks = NB * 16 / 256;
        spline4d_fp16_kernel<<<nblocks, 256, 0, stream>>>(
            u, (const half8*)hgrid, (float4*)d_out);
    }
}